// Round 11
// baseline (801.680 us; speedup 1.0000x reference)
//
#include <hip/hip_runtime.h>

// Fused SpikingDenseLayer: B=256, T=100, F=K=1024, U=1024.
// One block = one (batch b, 256-wide u-tile), 256 threads = 4 waves.
// v12 = v11 with the LDS footprint shrunk for full residency:
//  * v11: 45.6 KB -> 3 blocks/CU vs grid's exactly-4 -> 3-concurrent +
//    serial 1-block tail (occ 21%, wall 700 us vs 427 us VALU-active).
//  * BK 16->8: Ws dbuf 2x8 KB, As dbuf 2x3.2 KB. Same LDS-inst/FLOP,
//    same linear global_load_lds slot scheme. 128 barriers, each drain
//    covered by ~3.6k cyc of other-wave FMA at 4 blocks/CU.
//  * CHUNK 25->20 (5 scan chunks): scan region 21.1 KB < GEMM 22.8 KB.
//    Total LDS 22.8 KB -> 4 blocks/CU with 2x headroom (91 KB of 160).
//  * W-read layout u = {4ug,64+4ug,128+4ug,192+4ug}+{0..3}: conflict-free
//    (v11 measured 0). kk rolled (v4 spill lesson); no launch_bounds
//    min-waves arg. Spill tripwire: WRITE_SIZE must stay 103424 KB.
// Per-output FMA chain k-ascending, same expression forms as passing
// v5/v10/v11 -> currents bitwise identical; LIF scan math unchanged.

#define UN 256              // u-columns per block
#define BK 8                // k-slice staged per buffer
#define CSS 264             // Cs row stride in floats (256 + 8)
#define CHUNK 20            // t-rows per scan chunk (5 chunks)
#define TMAX 100

__device__ __forceinline__ void gload_lds16(const float* g, float* l) {
    __builtin_amdgcn_global_load_lds(
        (const __attribute__((address_space(1))) void*)g,
        (__attribute__((address_space(3))) void*)l,
        16, 0, 0);
}

__global__ __launch_bounds__(256) void fused_snn(
    const float* __restrict__ x,     // [B,T,F]
    const float* __restrict__ W,     // [F,U]
    const float* __restrict__ bias,  // [U]
    float* __restrict__ spikes,      // [B,T,U]
    float* __restrict__ counts,      // [B,U]
    int B, int T, int F, int U)
{
    // GEMM phase: As dbuf 2x800 + Ws dbuf 2x2048 = 5696 floats (22.8 KB).
    // Scan phase reuses the region as Cs[20][264] (5280 floats).
    __shared__ __align__(16) float smem[5696];
    float* As0 = smem;            // [100][8] linear
    float* As1 = smem + 800;
    float* Ws0 = smem + 1600;     // [8][256] linear
    float* Ws1 = smem + 3648;

    const int tid = threadIdx.x;
    const int tg  = tid >> 4;     // 0..15 -> t = i*16 + tg (wave-uniform tail)
    const int ug  = tid & 15;     // 0..15 -> u = 64*q + 4*ug + j
    const int u0  = blockIdx.x * UN;
    const int b   = blockIdx.y;

    float acc[7][16];
    #pragma unroll
    for (int i = 0; i < 7; i++)
        #pragma unroll
        for (int j = 0; j < 16; j++) acc[i][j] = 0.f;

    const float* xb = x + (size_t)b * T * F;

    // A staging: 100 rows x 32 B = 200 slots of 16 B; slot s -> row s>>1,
    // float-col (s&1)*4. Thread tid<200 handles slot tid; dest = slot*16 B.
    const float* ga0 = xb + (size_t)(tid >> 1) * F + (tid & 1) * 4;
    const int la0 = tid * 4;
    const bool aon = (tid < 200);
    const bool w0  = (tid < 64);             // wave 0 owns tail rows 96..99

    // W staging: 8 rows x 1024 B = 512 slots; thread covers slots tid
    // (row tid>>6, col (tid&63)*4) and tid+256 (row (tid>>6)+4).
    const float* gwr = W + (size_t)(tid >> 6) * U + u0 + (tid & 63) * 4;
    const int lw = tid * 4;

#define STAGE(abuf, wbuf, kof)                                          \
    do {                                                                \
        if (aon) gload_lds16(ga0 + (kof), (abuf) + la0);                \
        gload_lds16(gwr + (size_t)(kof) * U, (wbuf) + lw);              \
        gload_lds16(gwr + (size_t)((kof) + 4) * U, (wbuf) + 1024 + lw); \
    } while (0)

    // 16 FMAs: acc[i][q*4+j] += av * rq[j]   (u = 64q + 4ug + j)
#define FMA16(i, av, r0, r1, r2, r3)                                    \
    do {                                                                \
        acc[i][0]  += (av) * r0.x;  acc[i][1]  += (av) * r0.y;          \
        acc[i][2]  += (av) * r0.z;  acc[i][3]  += (av) * r0.w;          \
        acc[i][4]  += (av) * r1.x;  acc[i][5]  += (av) * r1.y;          \
        acc[i][6]  += (av) * r1.z;  acc[i][7]  += (av) * r1.w;          \
        acc[i][8]  += (av) * r2.x;  acc[i][9]  += (av) * r2.y;          \
        acc[i][10] += (av) * r2.z;  acc[i][11] += (av) * r2.w;          \
        acc[i][12] += (av) * r3.x;  acc[i][13] += (av) * r3.y;          \
        acc[i][14] += (av) * r3.z;  acc[i][15] += (av) * r3.w;          \
    } while (0)

#define COMPUTE(abuf, wbuf)                                             \
    do {                                                                \
        const float* ap  = (abuf) + tg * 8;                             \
        const float* wpk = (wbuf) + ug * 4;                             \
        _Pragma("unroll 1")                                             \
        for (int kk = 0; kk < BK; kk += 2) {                            \
            float2 a0 = *(const float2*)(ap + 0 * 128 + kk);            \
            float2 a1 = *(const float2*)(ap + 1 * 128 + kk);            \
            float2 a2 = *(const float2*)(ap + 2 * 128 + kk);            \
            float2 a3 = *(const float2*)(ap + 3 * 128 + kk);            \
            float2 a4 = *(const float2*)(ap + 4 * 128 + kk);            \
            float2 a5 = *(const float2*)(ap + 5 * 128 + kk);            \
            float2 a6;                                                  \
            if (w0) a6 = *(const float2*)(ap + 6 * 128 + kk);           \
            {   /* k = kk */                                            \
                const float* wr = wpk + kk * 256;                       \
                float4 p0 = *(const float4*)(wr);                       \
                float4 p1 = *(const float4*)(wr + 64);                  \
                float4 p2 = *(const float4*)(wr + 128);                 \
                float4 p3 = *(const float4*)(wr + 192);                 \
                FMA16(0, a0.x, p0, p1, p2, p3);                         \
                FMA16(1, a1.x, p0, p1, p2, p3);                         \
                FMA16(2, a2.x, p0, p1, p2, p3);                         \
                FMA16(3, a3.x, p0, p1, p2, p3);                         \
                FMA16(4, a4.x, p0, p1, p2, p3);                         \
                FMA16(5, a5.x, p0, p1, p2, p3);                         \
                if (w0) { FMA16(6, a6.x, p0, p1, p2, p3); }             \
            }                                                           \
            {   /* k = kk+1 */                                          \
                const float* wr = wpk + (kk + 1) * 256;                 \
                float4 q0 = *(const float4*)(wr);                       \
                float4 q1 = *(const float4*)(wr + 64);                  \
                float4 q2 = *(const float4*)(wr + 128);                 \
                float4 q3 = *(const float4*)(wr + 192);                 \
                FMA16(0, a0.y, q0, q1, q2, q3);                         \
                FMA16(1, a1.y, q0, q1, q2, q3);                         \
                FMA16(2, a2.y, q0, q1, q2, q3);                         \
                FMA16(3, a3.y, q0, q1, q2, q3);                         \
                FMA16(4, a4.y, q0, q1, q2, q3);                         \
                FMA16(5, a5.y, q0, q1, q2, q3);                         \
                if (w0) { FMA16(6, a6.y, q0, q1, q2, q3); }             \
            }                                                           \
        }                                                               \
    } while (0)

    // prologue: fill buffer set 0
    STAGE(As0, Ws0, 0);
    __syncthreads();   // auto vmcnt(0): tile 0 visible

    #pragma unroll 1
    for (int k0 = 0; k0 < F; k0 += 2 * BK) {
        STAGE(As1, Ws1, k0 + BK);             // async: next tile
        COMPUTE(As0, Ws0);
        __syncthreads();                      // drains STAGE, readers done
        if (k0 + 2 * BK < F) STAGE(As0, Ws0, k0 + 2 * BK);
        COMPUTE(As1, Ws1);
        __syncthreads();
    }

#undef STAGE
#undef COMPUTE
#undef FMA16

    // ---- bias (16 per thread; u = 64q + 4ug + j) ----
    float bb[16];
    {
        float4 b0 = *(const float4*)(bias + u0 + 4 * ug);
        float4 b1 = *(const float4*)(bias + u0 + 64 + 4 * ug);
        float4 b2 = *(const float4*)(bias + u0 + 128 + 4 * ug);
        float4 b3 = *(const float4*)(bias + u0 + 192 + 4 * ug);
        bb[0]=b0.x; bb[1]=b0.y; bb[2]=b0.z; bb[3]=b0.w;
        bb[4]=b1.x; bb[5]=b1.y; bb[6]=b1.z; bb[7]=b1.w;
        bb[8]=b2.x; bb[9]=b2.y; bb[10]=b2.z; bb[11]=b2.w;
        bb[12]=b3.x; bb[13]=b3.y; bb[14]=b3.z; bb[15]=b3.w;
    }

    // ---- chunked dump + LIF scan (5 x 20 t-rows; 256 u-cols) ----
    float vv = 0.f, cnt = 0.f;
    float* sp = spikes + (size_t)b * T * U + u0 + tid;

    #pragma unroll
    for (int c = 0; c < 5; c++) {
        #pragma unroll
        for (int i = 0; i < 7; i++) {
            const int t = i * 16 + tg;
            if (t >= c * CHUNK && t < c * CHUNK + CHUNK) {
                const int r = t - c * CHUNK;
                float4 d0, d1, d2, d3;
                d0.x = acc[i][0]  + bb[0];  d0.y = acc[i][1]  + bb[1];
                d0.z = acc[i][2]  + bb[2];  d0.w = acc[i][3]  + bb[3];
                d1.x = acc[i][4]  + bb[4];  d1.y = acc[i][5]  + bb[5];
                d1.z = acc[i][6]  + bb[6];  d1.w = acc[i][7]  + bb[7];
                d2.x = acc[i][8]  + bb[8];  d2.y = acc[i][9]  + bb[9];
                d2.z = acc[i][10] + bb[10]; d2.w = acc[i][11] + bb[11];
                d3.x = acc[i][12] + bb[12]; d3.y = acc[i][13] + bb[13];
                d3.z = acc[i][14] + bb[14]; d3.w = acc[i][15] + bb[15];
                float* row = smem + r * CSS;
                *(float4*)(row + 4 * ug)        = d0;
                *(float4*)(row + 64 + 4 * ug)   = d1;
                *(float4*)(row + 128 + 4 * ug)  = d2;
                *(float4*)(row + 192 + 4 * ug)  = d3;
            }
        }
        __syncthreads();
        {
#pragma clang fp contract(off)
            // rounding matches numpy elementwise exactly:
            // v = 0.25*v + round(0.75*c); spike = v > 1.0; v -= spike.
            for (int r = 0; r < CHUNK; r++) {
                float cval = smem[r * CSS + tid];
                vv = 0.25f * vv + 0.75f * cval;
                float s = (vv > 1.0f) ? 1.0f : 0.0f;
                vv -= s;
                cnt += s;
                sp[(size_t)(c * CHUNK + r) * U] = s;
            }
        }
        __syncthreads();   // scan done before next chunk overwrites Cs
    }
    counts[(size_t)b * U + u0 + tid] = cnt;
}

extern "C" void kernel_launch(void* const* d_in, const int* in_sizes, int n_in,
                              void* d_out, int out_size, void* d_ws, size_t ws_size,
                              hipStream_t stream) {
    const float* x    = (const float*)d_in[0];  // [B,T,F]
    const float* kern = (const float*)d_in[1];  // [F,U]
    const float* bias = (const float*)d_in[2];  // [U]
    float* out = (float*)d_out;

    const int U = in_sizes[2];                 // 1024
    const int F = in_sizes[1] / U;             // 1024
    const int R = in_sizes[0] / F;             // B*T = 25600
    const int B = out_size / U - R;            // 256
    const int T = R / B;                       // 100

    float* spikes = out;
    float* counts = out + (size_t)R * U;

    dim3 grid(U / UN, B);                      // (4, 256)
    fused_snn<<<grid, 256, 0, stream>>>(x, kern, bias, spikes, counts,
                                        B, T, F, U);
}